// Round 9
// baseline (9196.835 us; speedup 1.0000x reference)
//
#include <hip/hip_runtime.h>
#include <math.h>

typedef unsigned short u16;
typedef unsigned int   u32;

#define SQ   1024
#define BB   4
#define HH   768
#define NHD  12
#define HDD  64
#define FFD  3072
#define FFC  768    // FF chunk width (FFD/4)
#define NEXP 4
#define NTOK 4096   // SQ*BB

__device__ __forceinline__ float b2f(u16 h) {
  u32 u = ((u32)h) << 16;
  return __builtin_bit_cast(float, u);
}
__device__ __forceinline__ u16 f2b(float f) {
  u32 u = __builtin_bit_cast(u32, f);
  u32 r = u + 0x7FFFu + ((u >> 16) & 1u);
  return (u16)(r >> 16);
}

__global__ void zero_counts(int* counts) {
  if (threadIdx.x < NEXP) counts[threadIdx.x] = 0;
}

// ---------------- LayerNorm (768 wide), fp32 in -> bf16 out ----------------
__global__ __launch_bounds__(256) void ln_kernel(const float* __restrict__ x,
                                                 const float* __restrict__ w,
                                                 const float* __restrict__ b,
                                                 u16* __restrict__ o) {
  const int row = blockIdx.x, tid = threadIdx.x;
  const int lane = tid & 63, wv = tid >> 6;
  const float* xr = x + (size_t)row * HH;
  float v0 = xr[tid], v1 = xr[tid + 256], v2 = xr[tid + 512];
  float s1 = v0 + v1 + v2;
  float s2 = v0 * v0 + v1 * v1 + v2 * v2;
#pragma unroll
  for (int off = 32; off; off >>= 1) { s1 += __shfl_xor(s1, off); s2 += __shfl_xor(s2, off); }
  __shared__ float r1[4], r2[4];
  if (lane == 0) { r1[wv] = s1; r2[wv] = s2; }
  __syncthreads();
  float t1 = r1[0] + r1[1] + r1[2] + r1[3];
  float t2 = r2[0] + r2[1] + r2[2] + r2[3];
  float mean = t1 * (1.f / 768.f);
  float var  = fmaxf(t2 * (1.f / 768.f) - mean * mean, 0.f);
  float rstd = rsqrtf(var + 1e-5f);
  u16* orow = o + (size_t)row * HH;
  orow[tid]       = f2b((v0 - mean) * rstd * w[tid]       + b[tid]);
  orow[tid + 256] = f2b((v1 - mean) * rstd * w[tid + 256] + b[tid + 256]);
  orow[tid + 512] = f2b((v2 - mean) * rstd * w[tid + 512] + b[tid + 512]);
}

// ---------------- naive QKV: one thread per (t,p), LDS-broadcast A row ----------------
__global__ __launch_bounds__(256) void qkv_naive(
    const u16* __restrict__ A, const float* __restrict__ W,
    const float* __restrict__ bias,
    u16* __restrict__ Qb, u16* __restrict__ Kb, u16* __restrict__ Vb) {
  const int t = blockIdx.y;
  const int p = blockIdx.x * 256 + threadIdx.x;   // [0, 2304)
  __shared__ float a[HH];
  for (int h = threadIdx.x; h < HH; h += 256) a[h] = b2f(A[(size_t)t * HH + h]);
  __syncthreads();
  const float* wr = W + (size_t)p * HH;
  float acc = 0.f;
  for (int h = 0; h < HH; ++h) acc = fmaf(a[h], wr[h], acc);
  acc += bias[p];
  const int nh = p / 192, c = p % 192;
  const int s = t >> 2, b = t & 3;
  const size_t idx = ((size_t)(b * NHD + nh) * SQ + s) * HDD + (c & 63);
  const u16 hv = f2b(acc);
  if (c < 64) Qb[idx] = hv;
  else if (c < 128) Kb[idx] = hv;
  else Vb[idx] = hv;
}

// ---------------- naive attention: one block per (bh, s); two-pass softmax ----------------
__global__ __launch_bounds__(256) void attn_naive(
    const u16* __restrict__ Qb, const u16* __restrict__ Kb,
    const u16* __restrict__ Vb, u16* __restrict__ ctxo) {
  const int tid = threadIdx.x;
  const int s = blockIdx.x;
  const int bh = blockIdx.y;
  const size_t base = (size_t)bh * SQ * HDD;
  __shared__ float q[64];
  __shared__ float sc[SQ];
  __shared__ float red[4];
  __shared__ float pacc[4][64];
  if (tid < 64) q[tid] = b2f(Qb[base + (size_t)s * HDD + tid]);
  __syncthreads();
  const int nk = s + 1;          // causal: keys t <= s only
  for (int t = tid; t < nk; t += 256) {
    const u16* kr = Kb + base + (size_t)t * HDD;
    float d = 0.f;
    for (int h = 0; h < 64; ++h) d = fmaf(q[h], b2f(kr[h]), d);
    sc[t] = d * 0.125f;
  }
  __syncthreads();
  float m = -3.0e38f;
  for (int t = tid; t < nk; t += 256) m = fmaxf(m, sc[t]);
#pragma unroll
  for (int off = 32; off; off >>= 1) m = fmaxf(m, __shfl_xor(m, off));
  if ((tid & 63) == 0) red[tid >> 6] = m;
  __syncthreads();
  m = fmaxf(fmaxf(red[0], red[1]), fmaxf(red[2], red[3]));
  __syncthreads();
  float sum = 0.f;
  for (int t = tid; t < nk; t += 256) { float p = expf(sc[t] - m); sc[t] = p; sum += p; }
#pragma unroll
  for (int off = 32; off; off >>= 1) sum += __shfl_xor(sum, off);
  if ((tid & 63) == 0) red[tid >> 6] = sum;
  __syncthreads();
  const float l = red[0] + red[1] + red[2] + red[3];
  const int d = tid & 63, to = tid >> 6;
  float acc = 0.f;
  for (int t = to; t < nk; t += 4)
    acc = fmaf(sc[t], b2f(Vb[base + (size_t)t * HDD + d]), acc);
  pacc[to][d] = acc;
  __syncthreads();
  if (tid < 64) {
    const float o = (pacc[0][tid] + pacc[1][tid] + pacc[2][tid] + pacc[3][tid]) / l;
    const int b = bh / NHD, nh = bh % NHD;
    ctxo[(size_t)(s * BB + b) * HH + nh * HDD + tid] = f2b(o);
  }
}

// ---------------- naive dense: thread per (t,o); + bias + residual -> x1 fp32 ----------------
__global__ __launch_bounds__(256) void dense_naive(
    const u16* __restrict__ A, const float* __restrict__ W,
    const float* __restrict__ bias, const float* __restrict__ resid,
    float* __restrict__ x1) {
  const int t = blockIdx.y;
  const int o = blockIdx.x * 256 + threadIdx.x;   // [0, 768)
  __shared__ float a[HH];
  for (int h = threadIdx.x; h < HH; h += 256) a[h] = b2f(A[(size_t)t * HH + h]);
  __syncthreads();
  const float* wr = W + (size_t)o * HH;
  float acc = 0.f;
  for (int h = 0; h < HH; ++h) acc = fmaf(a[h], wr[h], acc);
  x1[(size_t)t * HH + o] = acc + bias[o] + resid[(size_t)t * HH + o];
}

// ---------------- gating: 1 wave per token; LN2 recomputed in fp32 from x1 ----------------
__global__ __launch_bounds__(256) void gate_kernel(
    const float* __restrict__ x1, const float* __restrict__ lnw,
    const float* __restrict__ lnb, const float* __restrict__ gw,
    float* __restrict__ eprob, int* __restrict__ counts, int* __restrict__ lists) {
  const int wv = threadIdx.x >> 6, lane = threadIdx.x & 63;
  const int t = (blockIdx.x << 2) + wv;
  const float* xr = x1 + (size_t)t * HH;
  float xv[12];
  float s1 = 0.f, s2 = 0.f;
#pragma unroll
  for (int j = 0; j < 12; ++j) {
    float x = xr[lane + (j << 6)];
    xv[j] = x;
    s1 += x; s2 += x * x;
  }
#pragma unroll
  for (int off = 32; off; off >>= 1) { s1 += __shfl_xor(s1, off); s2 += __shfl_xor(s2, off); }
  float mean = s1 * (1.f / 768.f);
  float var  = fmaxf(s2 * (1.f / 768.f) - mean * mean, 0.f);
  float rstd = rsqrtf(var + 1e-5f);
  float l0 = 0, l1 = 0, l2 = 0, l3 = 0;
#pragma unroll
  for (int j = 0; j < 12; ++j) {
    int h = lane + (j << 6);
    float x = (xv[j] - mean) * rstd * lnw[h] + lnb[h];
    l0 = fmaf(x, gw[h],        l0);
    l1 = fmaf(x, gw[HH + h],   l1);
    l2 = fmaf(x, gw[2*HH + h], l2);
    l3 = fmaf(x, gw[3*HH + h], l3);
  }
#pragma unroll
  for (int off = 32; off; off >>= 1) {
    l0 += __shfl_xor(l0, off); l1 += __shfl_xor(l1, off);
    l2 += __shfl_xor(l2, off); l3 += __shfl_xor(l3, off);
  }
  if (lane == 0) {
    float m = fmaxf(fmaxf(l0, l1), fmaxf(l2, l3));
    float d = expf(l0 - m) + expf(l1 - m) + expf(l2 - m) + expf(l3 - m);
    float best = l0; int idx = 0;
    if (l1 > best) { best = l1; idx = 1; }
    if (l2 > best) { best = l2; idx = 2; }
    if (l3 > best) { best = l3; idx = 3; }
    eprob[t] = expf(best - m) / d;
    int pos = atomicAdd(&counts[idx], 1);
    lists[idx * NTOK + pos] = t;
  }
}

// ---------------- naive MoE GEMM1 (FF chunk): thread per (token, f) ----------------
__global__ __launch_bounds__(256) void moe1_naive(
    const u16* __restrict__ ln2, const float* __restrict__ w1,
    const float* __restrict__ b1, const int* __restrict__ counts,
    const int* __restrict__ lists, u16* __restrict__ H1c, int fc0) {
  const int e = blockIdx.z;
  const int pos = blockIdx.y;
  if (pos >= counts[e]) return;
  const int r = lists[e * NTOK + pos];
  const int f = blockIdx.x * 256 + threadIdx.x;   // chunk-local [0, 768)
  __shared__ float a[HH];
  for (int h = threadIdx.x; h < HH; h += 256) a[h] = b2f(ln2[(size_t)r * HH + h]);
  __syncthreads();
  const float* wcol = w1 + (size_t)e * HH * FFD + fc0 + f;
  float acc = 0.f;
  for (int h = 0; h < HH; ++h) acc = fmaf(a[h], wcol[(size_t)h * FFD], acc);
  acc += b1[e * FFD + fc0 + f];
  float g = 0.5f * acc * (1.0f + erff(acc * 0.70710678118654752f));
  H1c[(size_t)r * FFC + f] = f2b(g);
}

// ---------------- naive MoE GEMM2 (FF chunk): accumulate into x1; last chunk -> out (FP32) ----------------
__global__ __launch_bounds__(256) void moe2_naive(
    const u16* __restrict__ H1c, const float* __restrict__ w2,
    const float* __restrict__ b2v, const int* __restrict__ counts,
    const int* __restrict__ lists, float* __restrict__ x1,
    const float* __restrict__ eprob, float* __restrict__ out,
    int fc0, int add_bias, int is_last) {
  const int e = blockIdx.z;
  const int pos = blockIdx.y;
  if (pos >= counts[e]) return;
  const int r = lists[e * NTOK + pos];
  const int o = blockIdx.x * 256 + threadIdx.x;   // [0, 768)
  __shared__ float a[FFC];
  for (int k = threadIdx.x; k < FFC; k += 256) a[k] = b2f(H1c[(size_t)r * FFC + k]);
  __syncthreads();
  const float* wcol = w2 + (size_t)e * FFD * HH + (size_t)fc0 * HH + o;
  float acc = 0.f;
  for (int k = 0; k < FFC; ++k) acc = fmaf(a[k], wcol[(size_t)k * HH], acc);
  if (add_bias) acc += b2v[e * HH + o];
  const float pr = eprob[r];
  const float res = x1[(size_t)r * HH + o] + pr * acc;
  if (is_last) out[(size_t)r * HH + o] = res;     // FP32 output
  else         x1[(size_t)r * HH + o] = res;
}

// ---------------- launch ----------------
// SEMANTICS (finally pinned): inputs FP32 (reference is jnp.float32; bf16-reading NaNs),
// output FP32 ("d_out holds the reference's OUTPUT dtype ... else float*").
// ws layout (max byte ~25.25MB, proven live in R6/R8):
//   [0,      6.29M)  Kb   -> x1 lower half after attn (fp32)
//   [6.29M, 12.58M)  Vb   -> x1 upper half
//   [12.58M,18.87M)  Qb   -> H1c during MoE
//   [18.87M,25.17M)  tmp: ln1o -> ctx -> ln2o (disjoint lifetimes)
//   [25.17M,  +82KB) eprob / counts / lists
extern "C" void kernel_launch(void* const* d_in, const int* in_sizes, int n_in,
                              void* d_out, int out_size, void* d_ws, size_t ws_size,
                              hipStream_t stream) {
  (void)in_sizes; (void)n_in; (void)out_size; (void)ws_size;
  const float* hidden  = (const float*)d_in[0];
  // d_in[1] attention_mask: known causal — unused
  const float* ln1w    = (const float*)d_in[2];
  const float* ln1b    = (const float*)d_in[3];
  const float* qkvw    = (const float*)d_in[4];
  const float* qkvb    = (const float*)d_in[5];
  const float* densew  = (const float*)d_in[6];
  const float* denseb  = (const float*)d_in[7];
  const float* ln2w    = (const float*)d_in[8];
  const float* ln2b    = (const float*)d_in[9];
  const float* gatew   = (const float*)d_in[10];
  const float* w1      = (const float*)d_in[11];
  const float* b1      = (const float*)d_in[12];
  const float* w2      = (const float*)d_in[13];
  const float* b2v     = (const float*)d_in[14];
  float* out = (float*)d_out;                 // FP32 output

  char* base = (char*)d_ws;
  const size_t T = (size_t)NTOK * HH;        // 3,145,728 elements
  u16*   Kb  = (u16*)base;                   // [0, T)
  u16*   Vb  = (u16*)base + T;               // [T, 2T)
  u16*   Qb  = (u16*)base + 2 * T;           // [2T, 3T)
  float* x1  = (float*)base;                 // overlays Kb+Vb after attention
  u16*   H1c = (u16*)base + 2 * T;           // overlays Qb during MoE
  u16*   tmp = (u16*)base + 3 * T;           // ln1o / ctx / ln2o
  char*  sm  = base + 4 * T * 2;             // byte 25,165,824
  float* eprob  = (float*)sm;                // 16,384 B
  int*   counts = (int*)(sm + 16384);        // 256 B
  int*   lists  = (int*)(sm + 16384 + 256);  // 65,536 B
  u16*   ln1o = tmp;
  u16*   ctx  = tmp;
  u16*   ln2o = tmp;

  zero_counts<<<1, 64, 0, stream>>>(counts);
  ln_kernel<<<NTOK, 256, 0, stream>>>(hidden, ln1w, ln1b, ln1o);
  qkv_naive<<<dim3(9, NTOK), 256, 0, stream>>>(ln1o, qkvw, qkvb, Qb, Kb, Vb);
  attn_naive<<<dim3(SQ, BB * NHD), 256, 0, stream>>>(Qb, Kb, Vb, ctx);
  dense_naive<<<dim3(3, NTOK), 256, 0, stream>>>(ctx, densew, denseb, hidden, x1);
  ln_kernel<<<NTOK, 256, 0, stream>>>(x1, ln2w, ln2b, ln2o);
  gate_kernel<<<NTOK / 4, 256, 0, stream>>>(x1, ln2w, ln2b, gatew, eprob, counts, lists);
  for (int c = 0; c < 4; ++c) {
    int fc0 = c * FFC;
    moe1_naive<<<dim3(3, NTOK, NEXP), 256, 0, stream>>>(ln2o, w1, b1, counts, lists, H1c, fc0);
    moe2_naive<<<dim3(3, NTOK, NEXP), 256, 0, stream>>>(H1c, w2, b2v, counts, lists, x1,
                                                        eprob, out, fc0,
                                                        /*add_bias=*/(c == 0),
                                                        /*is_last=*/(c == 3));
  }
}